// Round 7
// baseline (353.070 us; speedup 1.0000x reference)
//
#include <hip/hip_runtime.h>
#include <cstdint>
#include <cstddef>

// Problem constants (match reference)
#define NNODES 20000
#define NEDGES 640000
#define IN_F   128
#define CL1_F  256
#define CL2_F  128
#define OUT_F  10
#define BN_EPS 1e-5f

#define NC     256                // edge chunks for cnt/fill (2500 edges each)
#define CE     (NEDGES / NC)
#define HALFN  10000              // node half-range for LDS histograms

// conv sub-grids appended to the hist launch (hist is 2*NC blocks: chunk x half)
#define WB1    512                // W1: 512*256 elems, 1/thread
#define WB2    512                // W2: 4*256*128 elems, 1/thread
#define XB     ((NNODES * 16) / 256)   // x: 8 elems/thread -> 1250 blocks
// +1 trailing block zeroes the BN stat buffers (replaces hipMemsetAsync dispatch)

typedef unsigned short u16;

// ---------------- bf16 helpers ----------------

__device__ __forceinline__ float bf2f(u16 u) {
    union { uint32_t i; float f; } v; v.i = ((uint32_t)u) << 16; return v.f;
}
__device__ __forceinline__ u16 f2bf(float f) {
    union { float f; uint32_t i; } v; v.f = f;
    uint32_t r = v.i + 0x7fffu + ((v.i >> 16) & 1u);   // RNE
    return (u16)(r >> 16);
}
__device__ __forceinline__ void bf2x2(uint32_t u, float& lo, float& hi) {
    union { uint32_t i; float f; } a, b;
    a.i = u << 16; b.i = u & 0xffff0000u;
    lo = a.f; hi = b.f;
}
__device__ __forceinline__ uint32_t f2bf2(float lo, float hi) {
    return (uint32_t)f2bf(lo) | ((uint32_t)f2bf(hi) << 16);
}
__device__ __forceinline__ void unpack8(uint4 v, float* o) {
    bf2x2(v.x, o[0], o[1]); bf2x2(v.y, o[2], o[3]);
    bf2x2(v.z, o[4], o[5]); bf2x2(v.w, o[6], o[7]);
}

// ---------------- fused: CSC hist (blocks 0..2*NC) + conversions + BN zero ----------------

__launch_bounds__(256)
__global__ void build_hist_conv(const int* __restrict__ ei, const float* __restrict__ ew,
                                u16* __restrict__ cnt_h, u16* __restrict__ degq_h,
                                const float* __restrict__ W1, u16* __restrict__ W1t,
                                const float* __restrict__ W2, u16* __restrict__ W2t,
                                const float* __restrict__ x, u16* __restrict__ A1,
                                float* __restrict__ bnz,
                                int E, int N) {
    __shared__ uint32_t scnt[HALFN / 2];   // 20 KB
    __shared__ uint32_t sdeg[HALFN / 2];   // 20 KB
    int b = blockIdx.x;
    if (b < 2 * NC) {
        int chunk = b >> 1;
        int lo = (b & 1) * HALFN;
        int e0 = chunk * CE, e1 = e0 + CE;
        for (int i = threadIdx.x; i < HALFN / 2; i += 256) { scnt[i] = 0; sdeg[i] = 0; }
        __syncthreads();
        for (int e = e0 + threadIdx.x; e < e1; e += 256) {
            int r = ei[e];
            int c = ei[E + e];
            int ci = c - lo;
            if ((unsigned)ci < HALFN) atomicAdd(&scnt[ci >> 1], 1u << ((ci & 1) * 16));
            int ri = r - lo;
            if ((unsigned)ri < HALFN) {
                float w = (r == c) ? 0.0f : ew[e];
                uint32_t q = (uint32_t)(w * 1024.0f + 0.5f);
                atomicAdd(&sdeg[ri >> 1], q << ((ri & 1) * 16));
            }
        }
        __syncthreads();
        for (int i = threadIdx.x; i < HALFN; i += 256) {
            cnt_h[(size_t)chunk * N + lo + i]  = (u16)((scnt[i >> 1] >> ((i & 1) * 16)) & 0xffffu);
            degq_h[(size_t)chunk * N + lo + i] = (u16)((sdeg[i >> 1] >> ((i & 1) * 16)) & 0xffffu);
        }
    } else {
        int b2 = b - 2 * NC;
        if (b2 < WB1) {
            int i = b2 * 256 + threadIdx.x;
            int k = i >> 8, n = i & 255;
            W1t[(size_t)n * 512 + k] = f2bf(W1[i]);
        } else if (b2 < WB1 + WB2) {
            int j = (b2 - WB1) * 256 + threadIdx.x;
            int kc = j / (256 * 128);
            int rem = j - kc * 256 * 128;
            int ci = rem >> 7, co = rem & 127;
            W2t[(size_t)(kc * 128 + co) * 256 + ci] = f2bf(W2[j]);
        } else if (b2 < WB1 + WB2 + XB) {
            // x -> A1 slice0, vectorized 8 f32/thread (2x float4 -> uint4)
            int j = (b2 - WB1 - WB2) * 256 + threadIdx.x;   // < N*16
            int n = j >> 4, f = (j & 15) << 3;
            const float4* xp = (const float4*)(x + (size_t)n * 128 + f);
            float4 v0 = xp[0], v1 = xp[1];
            uint4 o;
            o.x = f2bf2(v0.x, v0.y); o.y = f2bf2(v0.z, v0.w);
            o.z = f2bf2(v1.x, v1.y); o.w = f2bf2(v1.z, v1.w);
            *(uint4*)(A1 + (size_t)n * 512 + f) = o;
        } else {
            // zero the 4*256-float BN stat region (bns1/bnq1/bns2/bnq2)
#pragma unroll
            for (int k = 0; k < 4; ++k) bnz[k * 256 + threadIdx.x] = 0.f;
        }
    }
}

// fused: per-node totals + dis + per-(chunk,node) fill-base deltas, one cnt_h sweep.
__global__ void reduce_dis_base(const u16* __restrict__ cnt_h, const u16* __restrict__ degq_h,
                                int* __restrict__ tot, float* __restrict__ dis,
                                u16* __restrict__ baseD, int N) {
    int i = blockIdx.x * blockDim.x + threadIdx.x;
    if (i >= N) return;
    int t = 0;
    uint32_t dq = 0;
#pragma unroll 8
    for (int c = 0; c < NC; ++c) {
        baseD[(size_t)c * N + i] = (u16)t;
        t  += cnt_h[(size_t)c * N + i];
        dq += degq_h[(size_t)c * N + i];
    }
    tot[i] = t;
    float d = (float)dq * (1.0f / 1024.0f);
    dis[i] = (d > 0.0f) ? rsqrtf(d) : 0.0f;
}

// ---------------- parallel single-block scan ----------------

#define SCHUNK  80
#define SSTRIDE 81

__launch_bounds__(256)
__global__ void scan_kernel(const int* __restrict__ tot, int* __restrict__ rowptr, int N) {
    __shared__ int s[250 * SSTRIDE];   // 81 KB
    __shared__ int wtot[4];
    int tid = threadIdx.x;

    const int4* t4 = (const int4*)tot;
    for (int i4 = tid; i4 < N / 4; i4 += 256) {
        int4 v = t4[i4];
        int i = i4 * 4;
        int c = i / SCHUNK;                 // 80 % 4 == 0: quad stays in one chunk
        int idx = c * SSTRIDE + (i - c * SCHUNK);
        s[idx] = v.x; s[idx + 1] = v.y; s[idx + 2] = v.z; s[idx + 3] = v.w;
    }
    __syncthreads();

    int tsum = 0;
    if (tid < 250) {
        int base = tid * SSTRIDE;
#pragma unroll 8
        for (int j = 0; j < SCHUNK; ++j) tsum += s[base + j];
    }

    int lane = tid & 63, wv = tid >> 6;
    int pre = tsum;
#pragma unroll
    for (int off = 1; off < 64; off <<= 1) {
        int v = __shfl_up(pre, off);
        if (lane >= off) pre += v;
    }
    if (lane == 63) wtot[wv] = pre;
    __syncthreads();
    int run = pre - tsum;                   // exclusive within wave
    for (int w = 0; w < wv; ++w) run += wtot[w];
    if (tid == 0) rowptr[N] = wtot[0] + wtot[1] + wtot[2] + wtot[3];

    if (tid < 250) {
        int base = tid * SSTRIDE;
        for (int j = 0; j < SCHUNK; ++j) { int v = s[base + j]; s[base + j] = run; run += v; }
    }
    __syncthreads();

    int4* r4 = (int4*)rowptr;
    for (int i4 = tid; i4 < N / 4; i4 += 256) {
        int i = i4 * 4;
        int c = i / SCHUNK;
        int idx = c * SSTRIDE + (i - c * SCHUNK);
        int4 v;
        v.x = s[idx]; v.y = s[idx + 1]; v.z = s[idx + 2]; v.w = s[idx + 3];
        r4[i4] = v;
    }
}

// fill CSC: packed 4-byte records (src u16 | bf16 weight << 16)
__launch_bounds__(256)
__global__ void fill_kernel(const int* __restrict__ ei, const float* __restrict__ ew,
                            const float* __restrict__ dis, const int* __restrict__ rowptr,
                            const u16* __restrict__ baseD,
                            uint32_t* __restrict__ erec, int E, int N) {
    __shared__ uint32_t srank[HALFN / 2];  // 20 KB
    int chunk = blockIdx.x >> 1;
    int lo = (blockIdx.x & 1) * HALFN;
    int e0 = chunk * CE, e1 = e0 + CE;
    for (int i = threadIdx.x; i < HALFN / 2; i += 256) srank[i] = 0;
    __syncthreads();
    for (int e = e0 + threadIdx.x; e < e1; e += 256) {
        int r = ei[e];
        int c = ei[E + e];
        int ci = c - lo;
        if ((unsigned)ci >= HALFN) continue;
        float w = (r == c) ? 0.0f : ew[e];
        float wn = -(dis[r] * w * dis[c]);   // * (2/lambda_max) = *1
        int sh = (ci & 1) * 16;
        uint32_t old = atomicAdd(&srank[ci >> 1], 1u << sh);
        int rank = (old >> sh) & 0xffff;
        int pos = rowptr[c] + (int)baseD[(size_t)chunk * N + c] + rank;
        erec[pos] = (uint32_t)r | ((uint32_t)f2bf(wn) << 16);
    }
}

// ---------------- general spmm (CSC gather, F=128, 16 threads/node, uint4, unroll-8) ----------------
// Proven R14/R18 core. R21: optional fused BN column stats (ssum/ssq) for the last
// layer-2 spmm — same reduction tree as the old bn_stats_bf (shfl_xor over the block's
// 16 nodes, LDS cross-wave, 256 atomics/block), computed on the bf16-rounded outputs.
__launch_bounds__(256)
__global__ void spmm_cl(const int* __restrict__ rowptr, const uint32_t* __restrict__ erec,
                        const u16* __restrict__ tin, int ldi,
                        const u16* __restrict__ t1, int ld1, float c1,
                        const u16* __restrict__ t2, int ld2, float c2,
                        u16* __restrict__ tout, int ldo,
                        const float* __restrict__ bias, int doReluBias,
                        float* __restrict__ ssum, float* __restrict__ ssq,
                        int N, float s) {
    __shared__ float reds[4][16][8];
    __shared__ float redq[4][16][8];
    int gid = blockIdx.x * blockDim.x + threadIdx.x;
    int n = gid >> 4;
    if (n >= N) return;
    int f = (gid & 15) << 3;
    int p = rowptr[n], pe = rowptr[n + 1];
    float acc[8] = {};
    for (; p + 7 < pe; p += 8) {
        uint32_t rr[8];
#pragma unroll
        for (int u = 0; u < 8; ++u) rr[u] = erec[p + u];
        uint4 vv[8];
#pragma unroll
        for (int u = 0; u < 8; ++u)
            vv[u] = *(const uint4*)(tin + (size_t)(rr[u] & 0xffffu) * ldi + f);
#pragma unroll
        for (int u = 0; u < 8; ++u) {
            float w = bf2f((u16)(rr[u] >> 16));
            float fa[8];
            unpack8(vv[u], fa);
#pragma unroll
            for (int q = 0; q < 8; ++q) acc[q] += w * fa[q];
        }
    }
    for (; p < pe; ++p) {
        uint32_t r0 = erec[p];
        uint4 v0 = *(const uint4*)(tin + (size_t)(r0 & 0xffffu) * ldi + f);
        float w0 = bf2f((u16)(r0 >> 16));
        float fa[8];
        unpack8(v0, fa);
#pragma unroll
        for (int q = 0; q < 8; ++q) acc[q] += w0 * fa[q];
    }
#pragma unroll
    for (int q = 0; q < 8; ++q) acc[q] *= s;
    if (t1) {
        uint4 v = *(const uint4*)(t1 + (size_t)n * ld1 + f);
        float fv[8]; unpack8(v, fv);
#pragma unroll
        for (int q = 0; q < 8; ++q) acc[q] += c1 * fv[q];
    }
    if (t2) {
        uint4 v = *(const uint4*)(t2 + (size_t)n * ld2 + f);
        float fv[8]; unpack8(v, fv);
#pragma unroll
        for (int q = 0; q < 8; ++q) acc[q] += c2 * fv[q];
    }
    if (doReluBias) {
#pragma unroll
        for (int q = 0; q < 8; ++q) acc[q] = fmaxf(acc[q] + bias[f + q], 0.0f);
    }
    u16 bb[8];
#pragma unroll
    for (int q = 0; q < 8; ++q) bb[q] = f2bf(acc[q]);
    uint4 o;
    o.x = (uint32_t)bb[0] | ((uint32_t)bb[1] << 16);
    o.y = (uint32_t)bb[2] | ((uint32_t)bb[3] << 16);
    o.z = (uint32_t)bb[4] | ((uint32_t)bb[5] << 16);
    o.w = (uint32_t)bb[6] | ((uint32_t)bb[7] << 16);
    *(uint4*)(tout + (size_t)n * ldo + f) = o;

    if (ssum) {
        // per-block column stats on the rounded stored values (grid is exact: no
        // returned threads — all lanes participate in shfl/barriers).
        int tid = threadIdx.x;
        float sv[8], qv[8];
#pragma unroll
        for (int q = 0; q < 8; ++q) { float vb = bf2f(bb[q]); sv[q] = vb; qv[q] = vb * vb; }
#pragma unroll
        for (int q = 0; q < 8; ++q) {
            sv[q] += __shfl_xor(sv[q], 16); sv[q] += __shfl_xor(sv[q], 32);
            qv[q] += __shfl_xor(qv[q], 16); qv[q] += __shfl_xor(qv[q], 32);
        }
        int wv = tid >> 6, ln = tid & 63;
        if (ln < 16) {
#pragma unroll
            for (int q = 0; q < 8; ++q) { reds[wv][ln][q] = sv[q]; redq[wv][ln][q] = qv[q]; }
        }
        __syncthreads();
        if (tid < 128) {
            int g = tid >> 3, q = tid & 7;
            float ss = reds[0][g][q] + reds[1][g][q] + reds[2][g][q] + reds[3][g][q];
            float qq = redq[0][g][q] + redq[1][g][q] + redq[2][g][q] + redq[3][g][q];
            atomicAdd(&ssum[(g << 3) + q], ss);
            atomicAdd(&ssq[(g << 3) + q], qq);
        }
    }
}

// ---------------- bf16 MFMA GEMM, 64x64 tile (+optional fused BN column stats) ----------------
// R21: reverted to the proven 64x64 (R4 best). 64x128 (R20) was neutral-to-negative:
// A panels are L2/L3-resident so re-read reduction bought nothing.

typedef __attribute__((ext_vector_type(8))) short short8;
typedef __attribute__((ext_vector_type(4))) float floatx4;

#define GBM 64
#define GBN 64
#define GBK 64

__launch_bounds__(256)
__global__ void gemm_mfma(const u16* __restrict__ A, const u16* __restrict__ Bt,
                          const float* __restrict__ bias, void* __restrict__ Cout,
                          float* __restrict__ ssum, float* __restrict__ ssq,
                          int M, int N, int K, int doRelu, int outBf) {
    __shared__ __align__(16) u16 As[GBM][GBK + 8];   // stride 144 B
    __shared__ __align__(16) u16 Bs[GBN][GBK + 8];
    __shared__ float colsum[GBN], colsq[GBN];

    int tid = threadIdx.x;
    int lane = tid & 63;
    int wave = tid >> 6;
    int wm = (wave & 1) * 32;
    int wn = (wave >> 1) * 32;
    int rowBase = blockIdx.x * GBM;
    int colBase = blockIdx.y * GBN;

    floatx4 acc[2][2];
#pragma unroll
    for (int i = 0; i < 2; ++i)
#pragma unroll
        for (int j = 0; j < 2; ++j) {
            acc[i][j][0] = 0.f; acc[i][j][1] = 0.f; acc[i][j][2] = 0.f; acc[i][j][3] = 0.f;
        }

    int sr = tid >> 3;             // 0..31
    int sc = (tid & 7) * 8;        // 0..56

    for (int k0 = 0; k0 < K; k0 += GBK) {
#pragma unroll
        for (int h = 0; h < 2; ++h) {
            int r = sr + h * 32;
            int gm = rowBase + r;
            uint4 v = make_uint4(0, 0, 0, 0);
            if (gm < M) v = *(const uint4*)(A + (size_t)gm * K + k0 + sc);
            *(uint4*)&As[r][sc] = v;
            int gn = colBase + r;                    // N multiple of 64 -> no guard
            uint4 w = *(const uint4*)(Bt + (size_t)gn * K + k0 + sc);
            *(uint4*)&Bs[r][sc] = w;
        }
        __syncthreads();

        int mrow = lane & 15;
        int kq = (lane >> 4) * 8;
#pragma unroll
        for (int kk = 0; kk < GBK; kk += 32) {
            short8 af[2], bfr[2];
#pragma unroll
            for (int i = 0; i < 2; ++i) af[i] = *(const short8*)&As[wm + i * 16 + mrow][kk + kq];
#pragma unroll
            for (int j = 0; j < 2; ++j) bfr[j] = *(const short8*)&Bs[wn + j * 16 + mrow][kk + kq];
#pragma unroll
            for (int i = 0; i < 2; ++i)
#pragma unroll
                for (int j = 0; j < 2; ++j)
                    acc[i][j] = __builtin_amdgcn_mfma_f32_16x16x32_bf16(af[i], bfr[j], acc[i][j], 0, 0, 0);
        }
        __syncthreads();
    }

    if (ssum) {
        if (tid < GBN) { colsum[tid] = 0.f; colsq[tid] = 0.f; }
        __syncthreads();
    }

    int cn0 = colBase + wn + (lane & 15);
    int rq = (lane >> 4) * 4;
    float* Cf = (float*)Cout;
    u16*   Cb = (u16*)Cout;
#pragma unroll
    for (int j = 0; j < 2; ++j) {
        float ps = 0.f, pq = 0.f;
        int n = cn0 + j * 16;
#pragma unroll
        for (int i = 0; i < 2; ++i) {
#pragma unroll
            for (int r = 0; r < 4; ++r) {
                int m = rowBase + wm + i * 16 + rq + r;
                if (m >= M) continue;
                float v = acc[i][j][r];
                if (bias) v += bias[n];
                if (doRelu) v = fmaxf(v, 0.0f);
                if (outBf) {
                    u16 bb = f2bf(v);
                    Cb[(size_t)m * N + n] = bb;
                    if (ssum) { float vb = bf2f(bb); ps += vb; pq += vb * vb; }
                } else {
                    Cf[(size_t)m * N + n] = v;
                }
            }
        }
        if (ssum) {
            int lc = wn + j * 16 + (lane & 15);
            atomicAdd(&colsum[lc], ps);
            atomicAdd(&colsq[lc], pq);
        }
    }
    if (ssum) {
        __syncthreads();
        if (tid < GBN) {
            atomicAdd(&ssum[colBase + tid], colsum[tid]);
            atomicAdd(&ssq[colBase + tid], colsq[tid]);
        }
    }
}

// fold BN1 into W2t (in place); bn_final computed inline per block.
__launch_bounds__(256)
__global__ void fold_w2(u16* __restrict__ W2t, const float* __restrict__ sums,
                        const float* __restrict__ sumsq, const float* __restrict__ gamma,
                        const float* __restrict__ beta, float* __restrict__ rowvec, float invN) {
    __shared__ float red[4];
    int n = blockIdx.x;
    int k = threadIdx.x;
    float m = sums[k] * invN;
    float var = sumsq[k] * invN - m * m;
    float sc = gamma[k] / sqrtf(var + BN_EPS);
    float sh = beta[k] - m * sc;
    float wf = bf2f(W2t[(size_t)n * 256 + k]);
    W2t[(size_t)n * 256 + k] = f2bf(wf * sc);
    float part = sh * wf;
#pragma unroll
    for (int off = 32; off > 0; off >>= 1) part += __shfl_down(part, off);
    if ((k & 63) == 0) red[k >> 6] = part;
    __syncthreads();
    if (k == 0) rowvec[n] = red[0] + red[1] + red[2] + red[3];
}

// ---------------- final linear with inline BN2 fold (bf16 input, vectorized) ----------------

__launch_bounds__(256)
__global__ void final_linear_bn(const u16* __restrict__ g, const float* __restrict__ Wlin,
                                const float* __restrict__ blin, const float* __restrict__ sums,
                                const float* __restrict__ sumsq, const float* __restrict__ gamma,
                                const float* __restrict__ beta, float* __restrict__ out,
                                int N, float invN) {
    __shared__ float Ws2[OUT_F][CL2_F + 4];   // +4 pad: rows land on different banks
    __shared__ float scs[CL2_F], shs[CL2_F];
    __shared__ float oc[OUT_F];
    int tid = threadIdx.x;
    if (tid < CL2_F) {
        float m = sums[tid] * invN;
        float var = sumsq[tid] * invN - m * m;
        float sc = gamma[tid] / sqrtf(var + BN_EPS);
        scs[tid] = sc;
        shs[tid] = beta[tid] - m * sc;
    }
    __syncthreads();
    for (int i = tid; i < OUT_F * CL2_F; i += 256) {
        int f = i & 127;
        Ws2[i >> 7][f] = Wlin[i] * scs[f];
    }
    __syncthreads();
    if (tid < OUT_F) {
        float a = blin[tid];
        const float* wr = Wlin + tid * CL2_F;
        for (int f = 0; f < CL2_F; ++f) a += shs[f] * wr[f];
        oc[tid] = a;
    }
    __syncthreads();
    int idx = blockIdx.x * 256 + tid;
    if (idx >= N * OUT_F) return;
    int n = idx / OUT_F, o = idx - n * OUT_F;
    const u16* gr = g + (size_t)n * CL2_F;
    const float* w2 = Ws2[o];
    float acc = 0.f;
#pragma unroll
    for (int f0 = 0; f0 < CL2_F; f0 += 8) {
        uint4 v = *(const uint4*)(gr + f0);
        float fa[8]; unpack8(v, fa);
        const float4* wp = (const float4*)(w2 + f0);
        float4 wa = wp[0], wb = wp[1];
        acc += fa[0] * wa.x + fa[1] * wa.y + fa[2] * wa.z + fa[3] * wa.w
             + fa[4] * wb.x + fa[5] * wb.y + fa[6] * wb.z + fa[7] * wb.w;
    }
    out[idx] = acc + oc[o];
}

// ---------------- host launch ----------------

extern "C" void kernel_launch(void* const* d_in, const int* in_sizes, int n_in,
                              void* d_out, int out_size, void* d_ws, size_t ws_size,
                              hipStream_t stream) {
    const float* x      = (const float*)d_in[0];
    const int*   ei     = (const int*)d_in[1];
    const float* ew     = (const float*)d_in[2];
    const float* W1     = (const float*)d_in[3];
    const float* b1     = (const float*)d_in[4];
    const float* W2     = (const float*)d_in[5];
    const float* b2     = (const float*)d_in[6];
    const float* gamma1 = (const float*)d_in[7];
    const float* beta1  = (const float*)d_in[8];
    const float* gamma2 = (const float*)d_in[9];
    const float* beta2  = (const float*)d_in[10];
    const float* Wlin   = (const float*)d_in[11];
    const float* blin   = (const float*)d_in[12];
    float* out = (float*)d_out;

    const int N = NNODES, E = NEDGES;

    // workspace (~80.2 MB)
    char* base = (char*)d_ws;
    u16*     cnt_h  = (u16*)    (base + 0);           // NC*N u16 = 10.24 MB
    u16*     degq_h = (u16*)    (base + 10240000);    // NC*N u16 = 10.24 MB
    u16*     baseD  = (u16*)    (base + 20480000);    // NC*N u16 = 10.24 MB
    u16*     A1     = (u16*)    (base + 30720000);    // N*512 bf16 = 20.48 MB
    u16*     Hc     = A1;                             // aliased (A1 dead after GEMM1)
    u16*     h1bf   = (u16*)    (base + 51200000);    // N*256 bf16 = 10.24 MB
    u16*     pbuf   = (u16*)    (base + 61440000);    // N*128 bf16 = 5.12 MB
    u16*     bb2    = (u16*)    (base + 66560000);    // N*128 bf16
    u16*     bb1    = (u16*)    (base + 71680000);    // N*128 bf16
    uint32_t* erec  = (uint32_t*)(base + 76800000);   // E*4 = 2.56 MB
    u16*     W1t    = (u16*)    (base + 79360000);    // 256*512 bf16 = 262144
    u16*     W2t    = (u16*)    (base + 79622144);    // 512*256 bf16 = 262144
    float*   rowvec = (float*)  (base + 79884288);    // 512 f32
    int*     rowptr = (int*)    (base + 79886336);    // N+1
    int*     tot    = (int*)    (base + 79966352);    // N
    float*   dis    = (float*)  (base + 80046352);    // N
    float*   bns1   = (float*)  (base + 80126352);    // 256 (BN1 sums)
    float*   bnq1    = bns1 + 256;                    // 256 (BN1 sumsq)
    float*   bns2    = bnq1 + 256;                    // 256 (BN2 sums; 128 used)
    float*   bnq2    = bns2 + 256;                    // 256 (BN2 sumsq)

    dim3 blk(256);

    // --- fused: CSC histograms (half-split) + conversions + BN-buffer zero ---
    build_hist_conv<<<dim3(2 * NC + WB1 + WB2 + XB + 1), blk, 0, stream>>>(
        ei, ew, cnt_h, degq_h, W1, W1t, W2, W2t, x, A1, bns1, E, N);
    // fused: totals + dis + baseD deltas in one cnt_h/degq_h sweep
    reduce_dis_base<<<dim3((N + 255) / 256), blk, 0, stream>>>(cnt_h, degq_h, tot, dis, baseD, N);
    scan_kernel<<<dim3(1), blk, 0, stream>>>(tot, rowptr, N);
    fill_kernel<<<dim3(2 * NC), blk, 0, stream>>>(ei, ew, dis, rowptr, baseD, erec, E, N);

    dim3 gS(((N << 4) + 255) / 256);   // spmm grid: 16 threads/node (1250 blocks, exact)

    // --- layer 1: A1 = [x|T1|T2|T3] bf16, ld 512 ---
    spmm_cl<<<gS, blk, 0, stream>>>(rowptr, erec, A1 + 0,   512, nullptr,  512, 0.f,
                                    nullptr, 512, 0.f, A1 + 128, 512, nullptr, 0,
                                    nullptr, nullptr, N, 1.0f);
    spmm_cl<<<gS, blk, 0, stream>>>(rowptr, erec, A1 + 128, 512, A1 + 0,   512, -1.f,
                                    nullptr, 512, 0.f, A1 + 256, 512, nullptr, 0,
                                    nullptr, nullptr, N, 2.0f);
    spmm_cl<<<gS, blk, 0, stream>>>(rowptr, erec, A1 + 256, 512, A1 + 128, 512, -1.f,
                                    nullptr, 512, 0.f, A1 + 384, 512, nullptr, 0,
                                    nullptr, nullptr, N, 2.0f);

    // --- GEMM1: h1bf = relu(A1 @ W1 + b1) bf16, fused BN1 column stats ---
    gemm_mfma<<<dim3((N + GBM - 1) / GBM, CL1_F / GBN), blk, 0, stream>>>(
        A1, W1t, b1, h1bf, bns1, bnq1, N, CL1_F, 512, 1, 1);

    // --- fold BN1 into W2t + rowvec ---
    fold_w2<<<dim3(512), dim3(256), 0, stream>>>(W2t, bns1, bnq1, gamma1, beta1, rowvec, 1.0f / N);

    // --- GEMM2: Hc = h1bf @ W2t' + rowvec  [M=20000, N=512, K=256] bf16 out ---
    gemm_mfma<<<dim3((N + GBM - 1) / GBM, 512 / GBN), blk, 0, stream>>>(
        h1bf, W2t, rowvec, Hc, nullptr, nullptr, N, 512, 256, 0, 1);

    // --- layer 2 via Clenshaw (F=128 spmms); BN2 stats fused into the last one ---
    spmm_cl<<<gS, blk, 0, stream>>>(rowptr, erec, Hc + 384, 512, Hc + 256, 512, 1.f,
                                    nullptr, 512, 0.f, bb2, 128, nullptr, 0,
                                    nullptr, nullptr, N, 2.0f);
    spmm_cl<<<gS, blk, 0, stream>>>(rowptr, erec, bb2, 128, Hc + 384, 512, -1.f,
                                    Hc + 128, 512, 1.f, bb1, 128, nullptr, 0,
                                    nullptr, nullptr, N, 2.0f);
    spmm_cl<<<gS, blk, 0, stream>>>(rowptr, erec, bb1, 128, bb2, 128, -1.f,
                                    Hc + 0, 512, 1.f, pbuf, 128, b2, 1,
                                    bns2, bnq2, N, 1.0f);

    // --- final linear with inline BN2 fold ---
    final_linear_bn<<<dim3((N * OUT_F + 255) / 256), blk, 0, stream>>>(
        pbuf, Wlin, blin, bns2, bnq2, gamma2, beta2, out, N, 1.0f / N);
}

// Round 8
// 330.662 us; speedup vs baseline: 1.0678x; 1.0678x over previous
//
#include <hip/hip_runtime.h>
#include <cstdint>
#include <cstddef>

// Problem constants (match reference)
#define NNODES 20000
#define NEDGES 640000
#define IN_F   128
#define CL1_F  256
#define CL2_F  128
#define OUT_F  10
#define BN_EPS 1e-5f

#define NC     256                // edge chunks for cnt/fill (2500 edges each)
#define CE     (NEDGES / NC)
#define HALFN  10000              // node half-range for LDS histograms

// conv sub-grids appended to the hist launch (hist is 2*NC blocks: chunk x half)
#define WB1    512                // W1: 512*256 elems, 1/thread
#define WB2    512                // W2: 4*256*128 elems, 1/thread
#define XB     ((NNODES * 16) / 256)   // x: 8 elems/thread -> 1250 blocks
// +1 trailing block zeroes the BN stat buffers (replaces hipMemsetAsync dispatch)

typedef unsigned short u16;

// ---------------- bf16 helpers ----------------

__device__ __forceinline__ float bf2f(u16 u) {
    union { uint32_t i; float f; } v; v.i = ((uint32_t)u) << 16; return v.f;
}
__device__ __forceinline__ u16 f2bf(float f) {
    union { float f; uint32_t i; } v; v.f = f;
    uint32_t r = v.i + 0x7fffu + ((v.i >> 16) & 1u);   // RNE
    return (u16)(r >> 16);
}
__device__ __forceinline__ void bf2x2(uint32_t u, float& lo, float& hi) {
    union { uint32_t i; float f; } a, b;
    a.i = u << 16; b.i = u & 0xffff0000u;
    lo = a.f; hi = b.f;
}
__device__ __forceinline__ uint32_t f2bf2(float lo, float hi) {
    return (uint32_t)f2bf(lo) | ((uint32_t)f2bf(hi) << 16);
}
__device__ __forceinline__ void unpack8(uint4 v, float* o) {
    bf2x2(v.x, o[0], o[1]); bf2x2(v.y, o[2], o[3]);
    bf2x2(v.z, o[4], o[5]); bf2x2(v.w, o[6], o[7]);
}

// ---------------- fused: CSC hist (blocks 0..2*NC) + conversions + BN zero ----------------

__launch_bounds__(256)
__global__ void build_hist_conv(const int* __restrict__ ei, const float* __restrict__ ew,
                                u16* __restrict__ cnt_h, u16* __restrict__ degq_h,
                                const float* __restrict__ W1, u16* __restrict__ W1t,
                                const float* __restrict__ W2, u16* __restrict__ W2t,
                                const float* __restrict__ x, u16* __restrict__ A1,
                                float* __restrict__ bnz,
                                int E, int N) {
    __shared__ uint32_t scnt[HALFN / 2];   // 20 KB
    __shared__ uint32_t sdeg[HALFN / 2];   // 20 KB
    int b = blockIdx.x;
    if (b < 2 * NC) {
        int chunk = b >> 1;
        int lo = (b & 1) * HALFN;
        int e0 = chunk * CE, e1 = e0 + CE;
        for (int i = threadIdx.x; i < HALFN / 2; i += 256) { scnt[i] = 0; sdeg[i] = 0; }
        __syncthreads();
        for (int e = e0 + threadIdx.x; e < e1; e += 256) {
            int r = ei[e];
            int c = ei[E + e];
            int ci = c - lo;
            if ((unsigned)ci < HALFN) atomicAdd(&scnt[ci >> 1], 1u << ((ci & 1) * 16));
            int ri = r - lo;
            if ((unsigned)ri < HALFN) {
                float w = (r == c) ? 0.0f : ew[e];
                uint32_t q = (uint32_t)(w * 1024.0f + 0.5f);
                atomicAdd(&sdeg[ri >> 1], q << ((ri & 1) * 16));
            }
        }
        __syncthreads();
        for (int i = threadIdx.x; i < HALFN; i += 256) {
            cnt_h[(size_t)chunk * N + lo + i]  = (u16)((scnt[i >> 1] >> ((i & 1) * 16)) & 0xffffu);
            degq_h[(size_t)chunk * N + lo + i] = (u16)((sdeg[i >> 1] >> ((i & 1) * 16)) & 0xffffu);
        }
    } else {
        int b2 = b - 2 * NC;
        if (b2 < WB1) {
            int i = b2 * 256 + threadIdx.x;
            int k = i >> 8, n = i & 255;
            W1t[(size_t)n * 512 + k] = f2bf(W1[i]);
        } else if (b2 < WB1 + WB2) {
            int j = (b2 - WB1) * 256 + threadIdx.x;
            int kc = j / (256 * 128);
            int rem = j - kc * 256 * 128;
            int ci = rem >> 7, co = rem & 127;
            W2t[(size_t)(kc * 128 + co) * 256 + ci] = f2bf(W2[j]);
        } else if (b2 < WB1 + WB2 + XB) {
            // x -> A1 slice0, vectorized 8 f32/thread (2x float4 -> uint4)
            int j = (b2 - WB1 - WB2) * 256 + threadIdx.x;   // < N*16
            int n = j >> 4, f = (j & 15) << 3;
            const float4* xp = (const float4*)(x + (size_t)n * 128 + f);
            float4 v0 = xp[0], v1 = xp[1];
            uint4 o;
            o.x = f2bf2(v0.x, v0.y); o.y = f2bf2(v0.z, v0.w);
            o.z = f2bf2(v1.x, v1.y); o.w = f2bf2(v1.z, v1.w);
            *(uint4*)(A1 + (size_t)n * 512 + f) = o;
        } else {
            // zero the 4*256-float BN stat region (bns1/bnq1/bns2/bnq2)
#pragma unroll
            for (int k = 0; k < 4; ++k) bnz[k * 256 + threadIdx.x] = 0.f;
        }
    }
}

// fused: per-node totals + dis + per-(chunk,node) fill-base deltas, one cnt_h sweep.
__global__ void reduce_dis_base(const u16* __restrict__ cnt_h, const u16* __restrict__ degq_h,
                                int* __restrict__ tot, float* __restrict__ dis,
                                u16* __restrict__ baseD, int N) {
    int i = blockIdx.x * blockDim.x + threadIdx.x;
    if (i >= N) return;
    int t = 0;
    uint32_t dq = 0;
#pragma unroll 8
    for (int c = 0; c < NC; ++c) {
        baseD[(size_t)c * N + i] = (u16)t;
        t  += cnt_h[(size_t)c * N + i];
        dq += degq_h[(size_t)c * N + i];
    }
    tot[i] = t;
    float d = (float)dq * (1.0f / 1024.0f);
    dis[i] = (d > 0.0f) ? rsqrtf(d) : 0.0f;
}

// ---------------- parallel single-block scan ----------------

#define SCHUNK  80
#define SSTRIDE 81

__launch_bounds__(256)
__global__ void scan_kernel(const int* __restrict__ tot, int* __restrict__ rowptr, int N) {
    __shared__ int s[250 * SSTRIDE];   // 81 KB
    __shared__ int wtot[4];
    int tid = threadIdx.x;

    const int4* t4 = (const int4*)tot;
    for (int i4 = tid; i4 < N / 4; i4 += 256) {
        int4 v = t4[i4];
        int i = i4 * 4;
        int c = i / SCHUNK;                 // 80 % 4 == 0: quad stays in one chunk
        int idx = c * SSTRIDE + (i - c * SCHUNK);
        s[idx] = v.x; s[idx + 1] = v.y; s[idx + 2] = v.z; s[idx + 3] = v.w;
    }
    __syncthreads();

    int tsum = 0;
    if (tid < 250) {
        int base = tid * SSTRIDE;
#pragma unroll 8
        for (int j = 0; j < SCHUNK; ++j) tsum += s[base + j];
    }

    int lane = tid & 63, wv = tid >> 6;
    int pre = tsum;
#pragma unroll
    for (int off = 1; off < 64; off <<= 1) {
        int v = __shfl_up(pre, off);
        if (lane >= off) pre += v;
    }
    if (lane == 63) wtot[wv] = pre;
    __syncthreads();
    int run = pre - tsum;                   // exclusive within wave
    for (int w = 0; w < wv; ++w) run += wtot[w];
    if (tid == 0) rowptr[N] = wtot[0] + wtot[1] + wtot[2] + wtot[3];

    if (tid < 250) {
        int base = tid * SSTRIDE;
        for (int j = 0; j < SCHUNK; ++j) { int v = s[base + j]; s[base + j] = run; run += v; }
    }
    __syncthreads();

    int4* r4 = (int4*)rowptr;
    for (int i4 = tid; i4 < N / 4; i4 += 256) {
        int i = i4 * 4;
        int c = i / SCHUNK;
        int idx = c * SSTRIDE + (i - c * SCHUNK);
        int4 v;
        v.x = s[idx]; v.y = s[idx + 1]; v.z = s[idx + 2]; v.w = s[idx + 3];
        r4[i4] = v;
    }
}

// fill CSC: packed 4-byte records (src u16 | bf16 weight << 16)
__launch_bounds__(256)
__global__ void fill_kernel(const int* __restrict__ ei, const float* __restrict__ ew,
                            const float* __restrict__ dis, const int* __restrict__ rowptr,
                            const u16* __restrict__ baseD,
                            uint32_t* __restrict__ erec, int E, int N) {
    __shared__ uint32_t srank[HALFN / 2];  // 20 KB
    int chunk = blockIdx.x >> 1;
    int lo = (blockIdx.x & 1) * HALFN;
    int e0 = chunk * CE, e1 = e0 + CE;
    for (int i = threadIdx.x; i < HALFN / 2; i += 256) srank[i] = 0;
    __syncthreads();
    for (int e = e0 + threadIdx.x; e < e1; e += 256) {
        int r = ei[e];
        int c = ei[E + e];
        int ci = c - lo;
        if ((unsigned)ci >= HALFN) continue;
        float w = (r == c) ? 0.0f : ew[e];
        float wn = -(dis[r] * w * dis[c]);   // * (2/lambda_max) = *1
        int sh = (ci & 1) * 16;
        uint32_t old = atomicAdd(&srank[ci >> 1], 1u << sh);
        int rank = (old >> sh) & 0xffff;
        int pos = rowptr[c] + (int)baseD[(size_t)chunk * N + c] + rank;
        erec[pos] = (uint32_t)r | ((uint32_t)f2bf(wn) << 16);
    }
}

// ---------------- general spmm (CSC gather, F=128, 16 threads/node, uint4, unroll-8) ----------------
// R22: exact R14/R18 hot loop restored (no LDS, no fused-BN epilogue). R21's fused
// epilogue slowed the main loop 25% even when disabled (LDS 0->4096 + epilogue codegen
// perturbation; spmm_cl 43.9 -> 56.3 us in top-5). Do not touch this kernel again.
__launch_bounds__(256)
__global__ void spmm_cl(const int* __restrict__ rowptr, const uint32_t* __restrict__ erec,
                        const u16* __restrict__ tin, int ldi,
                        const u16* __restrict__ t1, int ld1, float c1,
                        const u16* __restrict__ t2, int ld2, float c2,
                        u16* __restrict__ tout, int ldo,
                        const float* __restrict__ bias, int doReluBias,
                        int N, float s) {
    int gid = blockIdx.x * blockDim.x + threadIdx.x;
    int n = gid >> 4;
    if (n >= N) return;
    int f = (gid & 15) << 3;
    int p = rowptr[n], pe = rowptr[n + 1];
    float acc[8] = {};
    for (; p + 7 < pe; p += 8) {
        uint32_t rr[8];
#pragma unroll
        for (int u = 0; u < 8; ++u) rr[u] = erec[p + u];
        uint4 vv[8];
#pragma unroll
        for (int u = 0; u < 8; ++u)
            vv[u] = *(const uint4*)(tin + (size_t)(rr[u] & 0xffffu) * ldi + f);
#pragma unroll
        for (int u = 0; u < 8; ++u) {
            float w = bf2f((u16)(rr[u] >> 16));
            float fa[8];
            unpack8(vv[u], fa);
#pragma unroll
            for (int q = 0; q < 8; ++q) acc[q] += w * fa[q];
        }
    }
    for (; p < pe; ++p) {
        uint32_t r0 = erec[p];
        uint4 v0 = *(const uint4*)(tin + (size_t)(r0 & 0xffffu) * ldi + f);
        float w0 = bf2f((u16)(r0 >> 16));
        float fa[8];
        unpack8(v0, fa);
#pragma unroll
        for (int q = 0; q < 8; ++q) acc[q] += w0 * fa[q];
    }
#pragma unroll
    for (int q = 0; q < 8; ++q) acc[q] *= s;
    if (t1) {
        uint4 v = *(const uint4*)(t1 + (size_t)n * ld1 + f);
        float fv[8]; unpack8(v, fv);
#pragma unroll
        for (int q = 0; q < 8; ++q) acc[q] += c1 * fv[q];
    }
    if (t2) {
        uint4 v = *(const uint4*)(t2 + (size_t)n * ld2 + f);
        float fv[8]; unpack8(v, fv);
#pragma unroll
        for (int q = 0; q < 8; ++q) acc[q] += c2 * fv[q];
    }
    if (doReluBias) {
#pragma unroll
        for (int q = 0; q < 8; ++q) acc[q] = fmaxf(acc[q] + bias[f + q], 0.0f);
    }
    uint4 o;
    o.x = f2bf2(acc[0], acc[1]);
    o.y = f2bf2(acc[2], acc[3]);
    o.z = f2bf2(acc[4], acc[5]);
    o.w = f2bf2(acc[6], acc[7]);
    *(uint4*)(tout + (size_t)n * ldo + f) = o;
}

// ---------------- bf16 MFMA GEMM, 64x64 tile (+optional fused BN column stats) ----------------
// Proven R4 config: 64x64. (64x128 was neutral-to-negative: panels are L2/L3-resident.)

typedef __attribute__((ext_vector_type(8))) short short8;
typedef __attribute__((ext_vector_type(4))) float floatx4;

#define GBM 64
#define GBN 64
#define GBK 64

__launch_bounds__(256)
__global__ void gemm_mfma(const u16* __restrict__ A, const u16* __restrict__ Bt,
                          const float* __restrict__ bias, void* __restrict__ Cout,
                          float* __restrict__ ssum, float* __restrict__ ssq,
                          int M, int N, int K, int doRelu, int outBf) {
    __shared__ __align__(16) u16 As[GBM][GBK + 8];   // stride 144 B
    __shared__ __align__(16) u16 Bs[GBN][GBK + 8];
    __shared__ float colsum[GBN], colsq[GBN];

    int tid = threadIdx.x;
    int lane = tid & 63;
    int wave = tid >> 6;
    int wm = (wave & 1) * 32;
    int wn = (wave >> 1) * 32;
    int rowBase = blockIdx.x * GBM;
    int colBase = blockIdx.y * GBN;

    floatx4 acc[2][2];
#pragma unroll
    for (int i = 0; i < 2; ++i)
#pragma unroll
        for (int j = 0; j < 2; ++j) {
            acc[i][j][0] = 0.f; acc[i][j][1] = 0.f; acc[i][j][2] = 0.f; acc[i][j][3] = 0.f;
        }

    int sr = tid >> 3;             // 0..31
    int sc = (tid & 7) * 8;        // 0..56

    for (int k0 = 0; k0 < K; k0 += GBK) {
#pragma unroll
        for (int h = 0; h < 2; ++h) {
            int r = sr + h * 32;
            int gm = rowBase + r;
            uint4 v = make_uint4(0, 0, 0, 0);
            if (gm < M) v = *(const uint4*)(A + (size_t)gm * K + k0 + sc);
            *(uint4*)&As[r][sc] = v;
            int gn = colBase + r;                    // N multiple of 64 -> no guard
            uint4 w = *(const uint4*)(Bt + (size_t)gn * K + k0 + sc);
            *(uint4*)&Bs[r][sc] = w;
        }
        __syncthreads();

        int mrow = lane & 15;
        int kq = (lane >> 4) * 8;
#pragma unroll
        for (int kk = 0; kk < GBK; kk += 32) {
            short8 af[2], bfr[2];
#pragma unroll
            for (int i = 0; i < 2; ++i) af[i] = *(const short8*)&As[wm + i * 16 + mrow][kk + kq];
#pragma unroll
            for (int j = 0; j < 2; ++j) bfr[j] = *(const short8*)&Bs[wn + j * 16 + mrow][kk + kq];
#pragma unroll
            for (int i = 0; i < 2; ++i)
#pragma unroll
                for (int j = 0; j < 2; ++j)
                    acc[i][j] = __builtin_amdgcn_mfma_f32_16x16x32_bf16(af[i], bfr[j], acc[i][j], 0, 0, 0);
        }
        __syncthreads();
    }

    if (ssum) {
        if (tid < GBN) { colsum[tid] = 0.f; colsq[tid] = 0.f; }
        __syncthreads();
    }

    int cn0 = colBase + wn + (lane & 15);
    int rq = (lane >> 4) * 4;
    float* Cf = (float*)Cout;
    u16*   Cb = (u16*)Cout;
#pragma unroll
    for (int j = 0; j < 2; ++j) {
        float ps = 0.f, pq = 0.f;
        int n = cn0 + j * 16;
#pragma unroll
        for (int i = 0; i < 2; ++i) {
#pragma unroll
            for (int r = 0; r < 4; ++r) {
                int m = rowBase + wm + i * 16 + rq + r;
                if (m >= M) continue;
                float v = acc[i][j][r];
                if (bias) v += bias[n];
                if (doRelu) v = fmaxf(v, 0.0f);
                if (outBf) {
                    u16 bb = f2bf(v);
                    Cb[(size_t)m * N + n] = bb;
                    if (ssum) { float vb = bf2f(bb); ps += vb; pq += vb * vb; }
                } else {
                    Cf[(size_t)m * N + n] = v;
                }
            }
        }
        if (ssum) {
            int lc = wn + j * 16 + (lane & 15);
            atomicAdd(&colsum[lc], ps);
            atomicAdd(&colsq[lc], pq);
        }
    }
    if (ssum) {
        __syncthreads();
        if (tid < GBN) {
            atomicAdd(&ssum[colBase + tid], colsum[tid]);
            atomicAdd(&ssq[colBase + tid], colsq[tid]);
        }
    }
}

// ---------------- batchnorm stats (BN2 only; BN1 fused into GEMM1) ----------------
// Restored standalone (R4): fusing this into spmm regressed the spmm hot loop.

__launch_bounds__(256)
__global__ void bn_stats_bf(const u16* __restrict__ h, int N,
                            float* __restrict__ sums, float* __restrict__ sumsq) {
    __shared__ float reds[4][16][8];
    __shared__ float redq[4][16][8];
    int tid = threadIdx.x;
    int co = (tid & 15) << 3;      // col octet
    int rg = tid >> 4;             // 0..15 row group
    int r = blockIdx.x * 64 + rg;
    float s[8] = {}, q[8] = {};
#pragma unroll
    for (int i = 0; i < 4; ++i, r += 16) {
        if (r < N) {
            uint4 v = *(const uint4*)(h + (size_t)r * CL2_F + co);
            float fa[8]; unpack8(v, fa);
#pragma unroll
            for (int j = 0; j < 8; ++j) { s[j] += fa[j]; q[j] += fa[j] * fa[j]; }
        }
    }
#pragma unroll
    for (int j = 0; j < 8; ++j) {
        s[j] += __shfl_xor(s[j], 16); s[j] += __shfl_xor(s[j], 32);
        q[j] += __shfl_xor(q[j], 16); q[j] += __shfl_xor(q[j], 32);
    }
    int wv = tid >> 6, ln = tid & 63;
    if (ln < 16) {
#pragma unroll
        for (int j = 0; j < 8; ++j) { reds[wv][ln][j] = s[j]; redq[wv][ln][j] = q[j]; }
    }
    __syncthreads();
    if (tid < 128) {
        int g = tid >> 3, j = tid & 7;
        float ss = reds[0][g][j] + reds[1][g][j] + reds[2][g][j] + reds[3][g][j];
        float qq = redq[0][g][j] + redq[1][g][j] + redq[2][g][j] + redq[3][g][j];
        atomicAdd(&sums[(g << 3) + j], ss);
        atomicAdd(&sumsq[(g << 3) + j], qq);
    }
}

// fold BN1 into W2t (in place); bn_final computed inline per block.
__launch_bounds__(256)
__global__ void fold_w2(u16* __restrict__ W2t, const float* __restrict__ sums,
                        const float* __restrict__ sumsq, const float* __restrict__ gamma,
                        const float* __restrict__ beta, float* __restrict__ rowvec, float invN) {
    __shared__ float red[4];
    int n = blockIdx.x;
    int k = threadIdx.x;
    float m = sums[k] * invN;
    float var = sumsq[k] * invN - m * m;
    float sc = gamma[k] / sqrtf(var + BN_EPS);
    float sh = beta[k] - m * sc;
    float wf = bf2f(W2t[(size_t)n * 256 + k]);
    W2t[(size_t)n * 256 + k] = f2bf(wf * sc);
    float part = sh * wf;
#pragma unroll
    for (int off = 32; off > 0; off >>= 1) part += __shfl_down(part, off);
    if ((k & 63) == 0) red[k >> 6] = part;
    __syncthreads();
    if (k == 0) rowvec[n] = red[0] + red[1] + red[2] + red[3];
}

// ---------------- final linear with inline BN2 fold (bf16 input, vectorized) ----------------

__launch_bounds__(256)
__global__ void final_linear_bn(const u16* __restrict__ g, const float* __restrict__ Wlin,
                                const float* __restrict__ blin, const float* __restrict__ sums,
                                const float* __restrict__ sumsq, const float* __restrict__ gamma,
                                const float* __restrict__ beta, float* __restrict__ out,
                                int N, float invN) {
    __shared__ float Ws2[OUT_F][CL2_F + 4];   // +4 pad: rows land on different banks
    __shared__ float scs[CL2_F], shs[CL2_F];
    __shared__ float oc[OUT_F];
    int tid = threadIdx.x;
    if (tid < CL2_F) {
        float m = sums[tid] * invN;
        float var = sumsq[tid] * invN - m * m;
        float sc = gamma[tid] / sqrtf(var + BN_EPS);
        scs[tid] = sc;
        shs[tid] = beta[tid] - m * sc;
    }
    __syncthreads();
    for (int i = tid; i < OUT_F * CL2_F; i += 256) {
        int f = i & 127;
        Ws2[i >> 7][f] = Wlin[i] * scs[f];
    }
    __syncthreads();
    if (tid < OUT_F) {
        float a = blin[tid];
        const float* wr = Wlin + tid * CL2_F;
        for (int f = 0; f < CL2_F; ++f) a += shs[f] * wr[f];
        oc[tid] = a;
    }
    __syncthreads();
    int idx = blockIdx.x * 256 + tid;
    if (idx >= N * OUT_F) return;
    int n = idx / OUT_F, o = idx - n * OUT_F;
    const u16* gr = g + (size_t)n * CL2_F;
    const float* w2 = Ws2[o];
    float acc = 0.f;
#pragma unroll
    for (int f0 = 0; f0 < CL2_F; f0 += 8) {
        uint4 v = *(const uint4*)(gr + f0);
        float fa[8]; unpack8(v, fa);
        const float4* wp = (const float4*)(w2 + f0);
        float4 wa = wp[0], wb = wp[1];
        acc += fa[0] * wa.x + fa[1] * wa.y + fa[2] * wa.z + fa[3] * wa.w
             + fa[4] * wb.x + fa[5] * wb.y + fa[6] * wb.z + fa[7] * wb.w;
    }
    out[idx] = acc + oc[o];
}

// ---------------- host launch ----------------

extern "C" void kernel_launch(void* const* d_in, const int* in_sizes, int n_in,
                              void* d_out, int out_size, void* d_ws, size_t ws_size,
                              hipStream_t stream) {
    const float* x      = (const float*)d_in[0];
    const int*   ei     = (const int*)d_in[1];
    const float* ew     = (const float*)d_in[2];
    const float* W1     = (const float*)d_in[3];
    const float* b1     = (const float*)d_in[4];
    const float* W2     = (const float*)d_in[5];
    const float* b2     = (const float*)d_in[6];
    const float* gamma1 = (const float*)d_in[7];
    const float* beta1  = (const float*)d_in[8];
    const float* gamma2 = (const float*)d_in[9];
    const float* beta2  = (const float*)d_in[10];
    const float* Wlin   = (const float*)d_in[11];
    const float* blin   = (const float*)d_in[12];
    float* out = (float*)d_out;

    const int N = NNODES, E = NEDGES;

    // workspace (~80.2 MB)
    char* base = (char*)d_ws;
    u16*     cnt_h  = (u16*)    (base + 0);           // NC*N u16 = 10.24 MB
    u16*     degq_h = (u16*)    (base + 10240000);    // NC*N u16 = 10.24 MB
    u16*     baseD  = (u16*)    (base + 20480000);    // NC*N u16 = 10.24 MB
    u16*     A1     = (u16*)    (base + 30720000);    // N*512 bf16 = 20.48 MB
    u16*     Hc     = A1;                             // aliased (A1 dead after GEMM1)
    u16*     h1bf   = (u16*)    (base + 51200000);    // N*256 bf16 = 10.24 MB
    u16*     pbuf   = (u16*)    (base + 61440000);    // N*128 bf16 = 5.12 MB
    u16*     bb2    = (u16*)    (base + 66560000);    // N*128 bf16
    u16*     bb1    = (u16*)    (base + 71680000);    // N*128 bf16
    uint32_t* erec  = (uint32_t*)(base + 76800000);   // E*4 = 2.56 MB
    u16*     W1t    = (u16*)    (base + 79360000);    // 256*512 bf16 = 262144
    u16*     W2t    = (u16*)    (base + 79622144);    // 512*256 bf16 = 262144
    float*   rowvec = (float*)  (base + 79884288);    // 512 f32
    int*     rowptr = (int*)    (base + 79886336);    // N+1
    int*     tot    = (int*)    (base + 79966352);    // N
    float*   dis    = (float*)  (base + 80046352);    // N
    float*   bns1   = (float*)  (base + 80126352);    // 256 (BN1 sums)
    float*   bnq1    = bns1 + 256;                    // 256 (BN1 sumsq)
    float*   bns2    = bnq1 + 256;                    // 256 (BN2 sums; 128 used)
    float*   bnq2    = bns2 + 256;                    // 256 (BN2 sumsq)

    dim3 blk(256);

    // --- fused: CSC histograms (half-split) + conversions + BN-buffer zero ---
    build_hist_conv<<<dim3(2 * NC + WB1 + WB2 + XB + 1), blk, 0, stream>>>(
        ei, ew, cnt_h, degq_h, W1, W1t, W2, W2t, x, A1, bns1, E, N);
    // fused: totals + dis + baseD deltas in one cnt_h/degq_h sweep
    reduce_dis_base<<<dim3((N + 255) / 256), blk, 0, stream>>>(cnt_h, degq_h, tot, dis, baseD, N);
    scan_kernel<<<dim3(1), blk, 0, stream>>>(tot, rowptr, N);
    fill_kernel<<<dim3(2 * NC), blk, 0, stream>>>(ei, ew, dis, rowptr, baseD, erec, E, N);

    dim3 gS(((N << 4) + 255) / 256);   // spmm grid: 16 threads/node

    // --- layer 1: A1 = [x|T1|T2|T3] bf16, ld 512 ---
    spmm_cl<<<gS, blk, 0, stream>>>(rowptr, erec, A1 + 0,   512, nullptr,  512, 0.f,
                                    nullptr, 512, 0.f, A1 + 128, 512, nullptr, 0, N, 1.0f);
    spmm_cl<<<gS, blk, 0, stream>>>(rowptr, erec, A1 + 128, 512, A1 + 0,   512, -1.f,
                                    nullptr, 512, 0.f, A1 + 256, 512, nullptr, 0, N, 2.0f);
    spmm_cl<<<gS, blk, 0, stream>>>(rowptr, erec, A1 + 256, 512, A1 + 128, 512, -1.f,
                                    nullptr, 512, 0.f, A1 + 384, 512, nullptr, 0, N, 2.0f);

    // --- GEMM1: h1bf = relu(A1 @ W1 + b1) bf16, fused BN1 column stats ---
    gemm_mfma<<<dim3((N + GBM - 1) / GBM, CL1_F / GBN), blk, 0, stream>>>(
        A1, W1t, b1, h1bf, bns1, bnq1, N, CL1_F, 512, 1, 1);

    // --- fold BN1 into W2t + rowvec ---
    fold_w2<<<dim3(512), dim3(256), 0, stream>>>(W2t, bns1, bnq1, gamma1, beta1, rowvec, 1.0f / N);

    // --- GEMM2: Hc = h1bf @ W2t' + rowvec  [M=20000, N=512, K=256] bf16 out ---
    gemm_mfma<<<dim3((N + GBM - 1) / GBM, 512 / GBN), blk, 0, stream>>>(
        h1bf, W2t, rowvec, Hc, nullptr, nullptr, N, 512, 256, 0, 1);

    // --- layer 2 via Clenshaw (F=128 spmms) ---
    spmm_cl<<<gS, blk, 0, stream>>>(rowptr, erec, Hc + 384, 512, Hc + 256, 512, 1.f,
                                    nullptr, 512, 0.f, bb2, 128, nullptr, 0, N, 2.0f);
    spmm_cl<<<gS, blk, 0, stream>>>(rowptr, erec, bb2, 128, Hc + 384, 512, -1.f,
                                    Hc + 128, 512, 1.f, bb1, 128, nullptr, 0, N, 2.0f);
    spmm_cl<<<gS, blk, 0, stream>>>(rowptr, erec, bb1, 128, bb2, 128, -1.f,
                                    Hc + 0, 512, 1.f, pbuf, 128, b2, 1, N, 1.0f);

    // --- BN2 stats ---
    bn_stats_bf<<<dim3((N + 63) / 64), blk, 0, stream>>>(pbuf, N, bns2, bnq2);

    // --- final linear with inline BN2 fold ---
    final_linear_bn<<<dim3((N * OUT_F + 255) / 256), blk, 0, stream>>>(
        pbuf, Wlin, blin, bns2, bnq2, gamma2, beta2, out, N, 1.0f / N);
}